// Round 4
// baseline (5054.647 us; speedup 1.0000x reference)
//
#include <hip/hip_runtime.h>
#include <cstdint>
#include <cstddef>

#define KNB 20
#define NPTS 8192
#define BATCH 2
#define TOTAL (BATCH * NPTS)
#define SPLITS 8
#define CPS (NPTS / SPLITS)   // 1024 candidates per split
#define QB 4                  // queries per attention block

// ---------------------------------------------------------------------------
// K1: pointwise conv 3->64 + relu
// ---------------------------------------------------------------------------
__global__ __launch_bounds__(256) void k_conv(const float* __restrict__ pts,
                                              const float* __restrict__ w,
                                              const float* __restrict__ b,
                                              float* __restrict__ x0) {
  int gid = blockIdx.x * 256 + threadIdx.x;
  if (gid >= TOTAL * 64) return;
  int p = gid >> 6, c = gid & 63;
  float px = pts[p * 3 + 0], py = pts[p * 3 + 1], pz = pts[p * 3 + 2];
  float acc = b[c] + px * w[c] + py * w[64 + c] + pz * w[128 + c];
  x0[gid] = fmaxf(acc, 0.f);
}

// ---------------------------------------------------------------------------
// K2a: partial KNN (unchanged — bit-exact vs lax.top_k).
// ---------------------------------------------------------------------------
__global__ __launch_bounds__(256) void k_knn_part(const float* __restrict__ pts,
                                                  float2* __restrict__ part) {
  __shared__ float sx[CPS], sy[CPS], sz[CPS];
  int tid = threadIdx.x;
  int qb = blockIdx.x;
  int s = blockIdx.y;
  int q = qb * 256 + tid;
  int b = q >> 13;
  const float* pbase = pts + (size_t)b * NPTS * 3;
  const float* cbase = pbase + (size_t)s * CPS * 3;

  for (int c = tid; c < CPS; c += 256) {
    sx[c] = cbase[c * 3 + 0];
    sy[c] = cbase[c * 3 + 1];
    sz[c] = cbase[c * 3 + 2];
  }
  float qx = pts[q * 3 + 0], qy = pts[q * 3 + 1], qz = pts[q * 3 + 2];
  __syncthreads();

  float dist[KNB];
  int id[KNB];
#pragma unroll
  for (int j = 0; j < KNB; j++) { dist[j] = 3.402823466e38f; id[j] = 0; }

  int cid0 = s * CPS;
  for (int c = 0; c < CPS; c++) {
    float dx = qx - sx[c];
    float dy = qy - sy[c];
    float dz = qz - sz[c];
    float d2 = dx * dx + dy * dy + dz * dz;
    if (d2 < dist[KNB - 1]) {
      int cid = cid0 + c;
#pragma unroll
      for (int j = KNB - 1; j >= 0; j--) {
        bool cj = d2 < dist[j];
        bool cjm1 = (j > 0) && (d2 < dist[j - 1]);
        if (cj) {
          dist[j] = cjm1 ? dist[j - 1] : d2;
          id[j]   = cjm1 ? id[j - 1]   : cid;
        }
      }
    }
  }

  float2* dst = part + ((size_t)q * SPLITS + s) * KNB;
#pragma unroll
  for (int j = 0; j < KNB; j++)
    dst[j] = make_float2(dist[j], __int_as_float(id[j]));
}

// ---------------------------------------------------------------------------
// K2b: merge 8 sorted lists of 20 -> top-20 (unchanged).
// ---------------------------------------------------------------------------
__global__ __launch_bounds__(256) void k_knn_merge(const float2* __restrict__ part,
                                                   int* __restrict__ idxbuf) {
  __shared__ float sd[32][SPLITS][KNB];
  __shared__ int   si[32][SPLITS][KNB];
  __shared__ int   sp[32][SPLITS];
  int tid = threadIdx.x;
  int lq = tid >> 3, s = tid & 7;
  int q = blockIdx.x * 32 + lq;

  const float2* src = part + ((size_t)q * SPLITS + s) * KNB;
#pragma unroll
  for (int j = 0; j < KNB; j++) {
    float2 v = src[j];
    sd[lq][s][j] = v.x;
    si[lq][s][j] = __float_as_int(v.y);
  }
  sp[lq][s] = 0;
  __syncthreads();

  if (s == 0) {
    int bq = q >> 13;
    for (int step = 0; step < KNB; step++) {
      float best = 3.402823466e38f;
      int bs = 0, bi = 0;
      for (int s2 = 0; s2 < SPLITS; s2++) {
        int p = sp[lq][s2];
        float d = sd[lq][s2][p];
        if (d < best) { best = d; bs = s2; bi = si[lq][s2][p]; }
      }
      sp[lq][bs]++;
      idxbuf[q * KNB + step] = bq * NPTS + bi;
    }
  }
}

// ---------------------------------------------------------------------------
// K3: qkv GEMM (TOTAL,64) @ (64,192)
// ---------------------------------------------------------------------------
__global__ __launch_bounds__(256) void k_qkv(const float* __restrict__ x,
                                             const float* __restrict__ w,
                                             float* __restrict__ qkv) {
  int gid = blockIdx.x * 256 + threadIdx.x;
  if (gid >= TOTAL * 192) return;
  int p = gid / 192, c = gid % 192;
  const float* xr = x + (size_t)p * 64;
  float acc = 0.f;
#pragma unroll 16
  for (int k = 0; k < 64; k++) acc += xr[k] * w[k * 192 + c];
  qkv[gid] = acc;
}

// ---------------------------------------------------------------------------
// K4: fused attention, QB=4 queries/block, BARRIER-FREE phase B.
//  - aw1 read directly from global (131KB, L1/L2-resident; lane->1KB/instr
//    coalesced). No LDS staging, no phase-B __syncthreads.
//  - t1 staged in-place in s_inp[row][0:64]; rpe -> [64:128]; then [0:64]
//    overwritten with q-k. LDS = 41.7KB -> 3 blocks/CU (= VGPR cap 3 w/SIMD).
//  - per-thread weight columns (pw1/pw2 at fixed c) hoisted to registers.
// ---------------------------------------------------------------------------
__global__ __launch_bounds__(256, 3) void k_attn(
    const float* __restrict__ pos, const float* __restrict__ qkv,
    const int* __restrict__ idxbuf,
    const float* __restrict__ pw1, const float* __restrict__ pb1,
    const float* __restrict__ pw2, const float* __restrict__ pb2,
    const float* __restrict__ aw1, const float* __restrict__ ab1,
    const float* __restrict__ aw2, const float* __restrict__ ab2,
    float* __restrict__ xout) {
  __shared__ float s_inp[QB * KNB][128];   // 40 KB  [row=q*20+n][c]
  __shared__ float s_qi[QB][64];
  __shared__ float s_sim[QB * KNB];
  __shared__ int   s_nb[QB * KNB];

  int i0 = blockIdx.x * QB;
  int tid = threadIdx.x;
  int lane = tid & 63;
  int wv = tid >> 6;
  int cA = tid & 63;          // fixed channel for phases A1/A2

  {
    int q = tid >> 6, c = tid & 63;
    s_qi[q][c] = qkv[(size_t)(i0 + q) * 192 + c];
  }
  if (tid < QB * KNB) {
    int q = tid / KNB, n = tid % KNB;
    s_nb[q * KNB + n] = idxbuf[(i0 + q) * KNB + n];
  }
  __syncthreads();

  // A1: t1[row][h] = relu(rel . pw1[:,h] + pb1[h])  -> s_inp[row][0:64]
  {
    float w1x = pw1[cA], w1y = pw1[64 + cA], w1z = pw1[128 + cA];
    float b1h = pb1[cA];
#pragma unroll
    for (int j = 0; j < QB * KNB * 64 / 256; j++) {
      int it = tid + 256 * j;
      int row = it >> 6;
      int q = row / KNB;
      int g = s_nb[row];
      float rx = pos[(i0 + q) * 3 + 0] - pos[g * 3 + 0];
      float ry = pos[(i0 + q) * 3 + 1] - pos[g * 3 + 1];
      float rz = pos[(i0 + q) * 3 + 2] - pos[g * 3 + 2];
      float a = b1h + rx * w1x + ry * w1y + rz * w1z;
      s_inp[row][cA] = fmaxf(a, 0.f);
    }
  }
  __syncthreads();

  // A2: rpe[row][c] = t1[row] . pw2[:,c] + pb2[c] -> s_inp[row][64:128]
  {
    float pw2c[64];
#pragma unroll
    for (int h = 0; h < 64; h++) pw2c[h] = pw2[h * 64 + cA];
    float b2c = pb2[cA];
#pragma unroll
    for (int j = 0; j < QB * KNB * 64 / 256; j++) {
      int it = tid + 256 * j;
      int row = it >> 6;
      float acc = b2c;
      const float* t1r = &s_inp[row][0];
#pragma unroll 8
      for (int h = 0; h < 64; h++) acc += t1r[h] * pw2c[h];
      s_inp[row][64 + cA] = acc;
    }
  }
  __syncthreads();

  // A3: s_inp[row][0:64] = q - k_gather (overwrites t1; A2 reads are closed)
#pragma unroll
  for (int j = 0; j < QB * KNB * 64 / 256; j++) {
    int it = tid + 256 * j;
    int row = it >> 6;
    int q = row / KNB;
    int g = s_nb[row];
    float kv = qkv[(size_t)g * 192 + 64 + cA];
    s_inp[row][cA] = s_qi[q][cA] - kv;
  }
  __syncthreads();

  // B: hidden(80x256) = inp @ aw1 — aw1 straight from global, no barriers.
  int nb0 = 5 * wv;      // wave wv covers neighbors nb0..nb0+4 of EVERY query
  int c0 = 4 * lane;
  float acc[QB][5][4];
#pragma unroll
  for (int q = 0; q < QB; q++)
#pragma unroll
    for (int j = 0; j < 5; j++)
#pragma unroll
      for (int cc = 0; cc < 4; cc++) acc[q][j][cc] = 0.f;

#pragma unroll 2
  for (int kc = 0; kc < 128; kc += 4) {
    float4 a0 = *(const float4*)&aw1[(size_t)(kc + 0) * 256 + c0];
    float4 a1 = *(const float4*)&aw1[(size_t)(kc + 1) * 256 + c0];
    float4 a2 = *(const float4*)&aw1[(size_t)(kc + 2) * 256 + c0];
    float4 a3 = *(const float4*)&aw1[(size_t)(kc + 3) * 256 + c0];
#pragma unroll
    for (int q = 0; q < QB; q++)
#pragma unroll
      for (int j = 0; j < 5; j++) {
        float4 iv = *(float4*)&s_inp[q * KNB + nb0 + j][kc];
        acc[q][j][0] += iv.x * a0.x + iv.y * a1.x + iv.z * a2.x + iv.w * a3.x;
        acc[q][j][1] += iv.x * a0.y + iv.y * a1.y + iv.z * a2.y + iv.w * a3.y;
        acc[q][j][2] += iv.x * a0.z + iv.y * a1.z + iv.z * a2.z + iv.w * a3.z;
        acc[q][j][3] += iv.x * a0.w + iv.y * a1.w + iv.z * a2.w + iv.w * a3.w;
      }
  }

  // epilogue: relu(+ab1) . aw2, butterfly-reduce 64 lanes -> sim
  float4 b1 = *(const float4*)&ab1[c0];
  float4 w2 = *(const float4*)&aw2[c0];
  float ab2v = ab2[0];
#pragma unroll
  for (int q = 0; q < QB; q++)
#pragma unroll
    for (int j = 0; j < 5; j++) {
      float s = fmaxf(acc[q][j][0] + b1.x, 0.f) * w2.x +
                fmaxf(acc[q][j][1] + b1.y, 0.f) * w2.y +
                fmaxf(acc[q][j][2] + b1.z, 0.f) * w2.z +
                fmaxf(acc[q][j][3] + b1.w, 0.f) * w2.w;
#pragma unroll
      for (int off = 32; off > 0; off >>= 1) s += __shfl_xor(s, off);
      if (lane == 0) s_sim[q * KNB + nb0 + j] = s + ab2v;
    }
  __syncthreads();

  // C: softmax over K=20, out = sum attn * (v_gather + rpe)
  {
    int q = tid >> 6, c = tid & 63;
    float mx = -3.402823466e38f;
#pragma unroll
    for (int n = 0; n < KNB; n++) mx = fmaxf(mx, s_sim[q * KNB + n]);
    float e[KNB];
    float sum = 0.f;
#pragma unroll
    for (int n = 0; n < KNB; n++) {
      e[n] = expf(s_sim[q * KNB + n] - mx);
      sum += e[n];
    }
    float inv = 1.f / sum;
    float o = 0.f;
#pragma unroll
    for (int n = 0; n < KNB; n++) {
      int g = s_nb[q * KNB + n];
      float vnb = qkv[(size_t)g * 192 + 128 + c] + s_inp[q * KNB + n][64 + c];
      o += (e[n] * inv) * vnb;
    }
    xout[(size_t)(i0 + q) * 64 + c] = o;
  }
}

// ---------------------------------------------------------------------------
// K5: global max-pool + fc1 + fc3 (unchanged)
// ---------------------------------------------------------------------------
__global__ __launch_bounds__(256) void k_final(const float* __restrict__ x,
                                               const float* __restrict__ fc1w,
                                               const float* __restrict__ fc1b,
                                               const float* __restrict__ fc3w,
                                               const float* __restrict__ fc3b,
                                               float* __restrict__ out) {
  __shared__ float red[4][64];
  __shared__ float m[64];
  __shared__ float h1[32];
  int b = blockIdx.x;
  int tid = threadIdx.x;
  int c = tid & 63, pg = tid >> 6;
  float mx = -3.402823466e38f;
  for (int p = pg; p < NPTS; p += 4)
    mx = fmaxf(mx, x[((size_t)b * NPTS + p) * 64 + c]);
  red[pg][c] = mx;
  __syncthreads();
  if (tid < 64)
    m[c] = fmaxf(fmaxf(red[0][c], red[1][c]), fmaxf(red[2][c], red[3][c]));
  __syncthreads();
  if (tid < 32) {
    float a = fc1b[tid];
#pragma unroll 8
    for (int k = 0; k < 64; k++) a += m[k] * fc1w[k * 32 + tid];
    h1[tid] = fmaxf(a, 0.f);
  }
  __syncthreads();
  if (tid < 3) {
    float a = fc3b[tid];
#pragma unroll
    for (int k = 0; k < 32; k++) a += h1[k] * fc3w[k * 3 + tid];
    out[b * 3 + tid] = a;
  }
}

// ---------------------------------------------------------------------------
extern "C" void kernel_launch(void* const* d_in, const int* in_sizes, int n_in,
                              void* d_out, int out_size, void* d_ws,
                              size_t ws_size, hipStream_t stream) {
  const float* pts    = (const float*)d_in[0];
  const float* conv_w = (const float*)d_in[1];
  const float* conv_b = (const float*)d_in[2];
  const float* fc1w = (const float*)d_in[21];
  const float* fc1b = (const float*)d_in[22];
  const float* fc3w = (const float*)d_in[23];
  const float* fc3b = (const float*)d_in[24];
  float* outp = (float*)d_out;

  char* ws = (char*)d_ws;
  float*  x0   = (float*) (ws);
  int*    idx  = (int*)   (ws + (size_t)4 * 1048576);
  float2* part = (float2*)(ws + (size_t)6 * 1048576);
  float*  qkv  = (float*) (ws + (size_t)6 * 1048576);   // reuses part region
  float*  x1   = (float*) (ws + (size_t)19 * 1048576);
  float*  x2   = (float*) (ws + (size_t)19 * 1048576 + 4194304);

  k_conv<<<(TOTAL * 64 + 255) / 256, 256, 0, stream>>>(pts, conv_w, conv_b, x0);
  k_knn_part<<<dim3(TOTAL / 256, SPLITS), 256, 0, stream>>>(pts, part);
  k_knn_merge<<<TOTAL / 32, 256, 0, stream>>>(part, idx);

  // layer 1
  {
    const float* qkvw = (const float*)d_in[3];
    k_qkv<<<(TOTAL * 192 + 255) / 256, 256, 0, stream>>>(x0, qkvw, qkv);
    k_attn<<<TOTAL / QB, 256, 0, stream>>>(
        pts, qkv, idx, (const float*)d_in[4], (const float*)d_in[5],
        (const float*)d_in[6], (const float*)d_in[7], (const float*)d_in[8],
        (const float*)d_in[9], (const float*)d_in[10], (const float*)d_in[11],
        x1);
  }
  // layer 2
  {
    const float* qkvw = (const float*)d_in[12];
    k_qkv<<<(TOTAL * 192 + 255) / 256, 256, 0, stream>>>(x1, qkvw, qkv);
    k_attn<<<TOTAL / QB, 256, 0, stream>>>(
        pts, qkv, idx, (const float*)d_in[13], (const float*)d_in[14],
        (const float*)d_in[15], (const float*)d_in[16], (const float*)d_in[17],
        (const float*)d_in[18], (const float*)d_in[19], (const float*)d_in[20],
        x2);
  }
  k_final<<<BATCH, 256, 0, stream>>>(x2, fc1w, fc1b, fc3w, fc3b, outp);
}

// Round 5
// 3602.987 us; speedup vs baseline: 1.4029x; 1.4029x over previous
//
#include <hip/hip_runtime.h>
#include <cstdint>
#include <cstddef>

#define KNB 20
#define NPTS 8192
#define BATCH 2
#define TOTAL (BATCH * NPTS)
#define SPLITS 8
#define CPS (NPTS / SPLITS)   // 1024 candidates per split
#define QB 4                  // queries per attention block

// ---------------------------------------------------------------------------
// K1: pointwise conv 3->64 + relu
// ---------------------------------------------------------------------------
__global__ __launch_bounds__(256) void k_conv(const float* __restrict__ pts,
                                              const float* __restrict__ w,
                                              const float* __restrict__ b,
                                              float* __restrict__ x0) {
  int gid = blockIdx.x * 256 + threadIdx.x;
  if (gid >= TOTAL * 64) return;
  int p = gid >> 6, c = gid & 63;
  float px = pts[p * 3 + 0], py = pts[p * 3 + 1], pz = pts[p * 3 + 2];
  float acc = b[c] + px * w[c] + py * w[64 + c] + pz * w[128 + c];
  x0[gid] = fmaxf(acc, 0.f);
}

// ---------------------------------------------------------------------------
// K2a: partial KNN (unchanged — bit-exact vs lax.top_k).
// ---------------------------------------------------------------------------
__global__ __launch_bounds__(256) void k_knn_part(const float* __restrict__ pts,
                                                  float2* __restrict__ part) {
  __shared__ float sx[CPS], sy[CPS], sz[CPS];
  int tid = threadIdx.x;
  int qb = blockIdx.x;
  int s = blockIdx.y;
  int q = qb * 256 + tid;
  int b = q >> 13;
  const float* pbase = pts + (size_t)b * NPTS * 3;
  const float* cbase = pbase + (size_t)s * CPS * 3;

  for (int c = tid; c < CPS; c += 256) {
    sx[c] = cbase[c * 3 + 0];
    sy[c] = cbase[c * 3 + 1];
    sz[c] = cbase[c * 3 + 2];
  }
  float qx = pts[q * 3 + 0], qy = pts[q * 3 + 1], qz = pts[q * 3 + 2];
  __syncthreads();

  float dist[KNB];
  int id[KNB];
#pragma unroll
  for (int j = 0; j < KNB; j++) { dist[j] = 3.402823466e38f; id[j] = 0; }

  int cid0 = s * CPS;
  for (int c = 0; c < CPS; c++) {
    float dx = qx - sx[c];
    float dy = qy - sy[c];
    float dz = qz - sz[c];
    float d2 = dx * dx + dy * dy + dz * dz;
    if (d2 < dist[KNB - 1]) {
      int cid = cid0 + c;
#pragma unroll
      for (int j = KNB - 1; j >= 0; j--) {
        bool cj = d2 < dist[j];
        bool cjm1 = (j > 0) && (d2 < dist[j - 1]);
        if (cj) {
          dist[j] = cjm1 ? dist[j - 1] : d2;
          id[j]   = cjm1 ? id[j - 1]   : cid;
        }
      }
    }
  }

  float2* dst = part + ((size_t)q * SPLITS + s) * KNB;
#pragma unroll
  for (int j = 0; j < KNB; j++)
    dst[j] = make_float2(dist[j], __int_as_float(id[j]));
}

// ---------------------------------------------------------------------------
// K2b: merge 8 sorted lists of 20 -> top-20 (unchanged).
// ---------------------------------------------------------------------------
__global__ __launch_bounds__(256) void k_knn_merge(const float2* __restrict__ part,
                                                   int* __restrict__ idxbuf) {
  __shared__ float sd[32][SPLITS][KNB];
  __shared__ int   si[32][SPLITS][KNB];
  __shared__ int   sp[32][SPLITS];
  int tid = threadIdx.x;
  int lq = tid >> 3, s = tid & 7;
  int q = blockIdx.x * 32 + lq;

  const float2* src = part + ((size_t)q * SPLITS + s) * KNB;
#pragma unroll
  for (int j = 0; j < KNB; j++) {
    float2 v = src[j];
    sd[lq][s][j] = v.x;
    si[lq][s][j] = __float_as_int(v.y);
  }
  sp[lq][s] = 0;
  __syncthreads();

  if (s == 0) {
    int bq = q >> 13;
    for (int step = 0; step < KNB; step++) {
      float best = 3.402823466e38f;
      int bs = 0, bi = 0;
      for (int s2 = 0; s2 < SPLITS; s2++) {
        int p = sp[lq][s2];
        float d = sd[lq][s2][p];
        if (d < best) { best = d; bs = s2; bi = si[lq][s2][p]; }
      }
      sp[lq][bs]++;
      idxbuf[q * KNB + step] = bq * NPTS + bi;
    }
  }
}

// ---------------------------------------------------------------------------
// K3: qkv GEMM (TOTAL,64) @ (64,192)
// ---------------------------------------------------------------------------
__global__ __launch_bounds__(256) void k_qkv(const float* __restrict__ x,
                                             const float* __restrict__ w,
                                             float* __restrict__ qkv) {
  int gid = blockIdx.x * 256 + threadIdx.x;
  if (gid >= TOTAL * 192) return;
  int p = gid / 192, c = gid % 192;
  const float* xr = x + (size_t)p * 64;
  float acc = 0.f;
#pragma unroll 16
  for (int k = 0; k < 64; k++) acc += xr[k] * w[k * 192 + c];
  qkv[gid] = acc;
}

// ---------------------------------------------------------------------------
// K4: fused attention, QB=4 queries/block, BARRIER-FREE phase B.
//  - aw1 read directly from global (131KB, L1/L2-resident; 1KB/wave/instr
//    coalesced). No LDS staging, no phase-B __syncthreads.
//  - t1 staged in-place in s_inp[row][0:64]; rpe -> [64:128]; then [0:64]
//    overwritten with q-k. LDS = 41.7KB -> 3 blocks/CU.
//  - A2 reads pw2 DIRECTLY from global (L1 broadcast). NO private arrays:
//    R4's pw2c[64] register-preload got scratch-allocated (dynamic index
//    under partial unroll) -> 7.26 GB/dispatch spill traffic, 2.1ms. Never
//    use a partially-unrolled-indexed local array here.
// ---------------------------------------------------------------------------
__global__ __launch_bounds__(256, 3) void k_attn(
    const float* __restrict__ pos, const float* __restrict__ qkv,
    const int* __restrict__ idxbuf,
    const float* __restrict__ pw1, const float* __restrict__ pb1,
    const float* __restrict__ pw2, const float* __restrict__ pb2,
    const float* __restrict__ aw1, const float* __restrict__ ab1,
    const float* __restrict__ aw2, const float* __restrict__ ab2,
    float* __restrict__ xout) {
  __shared__ float s_inp[QB * KNB][128];   // 40 KB  [row=q*20+n][c]
  __shared__ float s_qi[QB][64];
  __shared__ float s_sim[QB * KNB];
  __shared__ int   s_nb[QB * KNB];

  int i0 = blockIdx.x * QB;
  int tid = threadIdx.x;
  int lane = tid & 63;
  int wv = tid >> 6;
  int cA = tid & 63;          // fixed channel for phases A1/A2/A3

  {
    int q = tid >> 6, c = tid & 63;
    s_qi[q][c] = qkv[(size_t)(i0 + q) * 192 + c];
  }
  if (tid < QB * KNB) {
    int q = tid / KNB, n = tid % KNB;
    s_nb[q * KNB + n] = idxbuf[(i0 + q) * KNB + n];
  }
  __syncthreads();

  // A1: t1[row][h] = relu(rel . pw1[:,h] + pb1[h])  -> s_inp[row][0:64]
  {
    float w1x = pw1[cA], w1y = pw1[64 + cA], w1z = pw1[128 + cA];
    float b1h = pb1[cA];
#pragma unroll
    for (int j = 0; j < QB * KNB * 64 / 256; j++) {
      int it = tid + 256 * j;
      int row = it >> 6;
      int q = row / KNB;
      int g = s_nb[row];
      float rx = pos[(i0 + q) * 3 + 0] - pos[g * 3 + 0];
      float ry = pos[(i0 + q) * 3 + 1] - pos[g * 3 + 1];
      float rz = pos[(i0 + q) * 3 + 2] - pos[g * 3 + 2];
      float a = b1h + rx * w1x + ry * w1y + rz * w1z;
      s_inp[row][cA] = fmaxf(a, 0.f);
    }
  }
  __syncthreads();

  // A2: rpe[row][c] = t1[row] . pw2[:,c] + pb2[c] -> s_inp[row][64:128]
  //     pw2 read straight from global (L1-cached, coalesced across lanes).
  {
    float b2c = pb2[cA];
#pragma unroll
    for (int j = 0; j < QB * KNB * 64 / 256; j++) {
      int it = tid + 256 * j;
      int row = it >> 6;
      float acc = b2c;
      const float* t1r = &s_inp[row][0];
#pragma unroll 8
      for (int h = 0; h < 64; h++) acc += t1r[h] * pw2[h * 64 + cA];
      s_inp[row][64 + cA] = acc;
    }
  }
  __syncthreads();

  // A3: s_inp[row][0:64] = q - k_gather (overwrites t1; A2 reads are closed)
#pragma unroll
  for (int j = 0; j < QB * KNB * 64 / 256; j++) {
    int it = tid + 256 * j;
    int row = it >> 6;
    int q = row / KNB;
    int g = s_nb[row];
    float kv = qkv[(size_t)g * 192 + 64 + cA];
    s_inp[row][cA] = s_qi[q][cA] - kv;
  }
  __syncthreads();

  // B: hidden(80x256) = inp @ aw1 — aw1 straight from global, no barriers.
  int nb0 = 5 * wv;      // wave wv covers neighbors nb0..nb0+4 of EVERY query
  int c0 = 4 * lane;
  float acc[QB][5][4];
#pragma unroll
  for (int q = 0; q < QB; q++)
#pragma unroll
    for (int j = 0; j < 5; j++)
#pragma unroll
      for (int cc = 0; cc < 4; cc++) acc[q][j][cc] = 0.f;

#pragma unroll 2
  for (int kc = 0; kc < 128; kc += 4) {
    float4 a0 = *(const float4*)&aw1[(size_t)(kc + 0) * 256 + c0];
    float4 a1 = *(const float4*)&aw1[(size_t)(kc + 1) * 256 + c0];
    float4 a2 = *(const float4*)&aw1[(size_t)(kc + 2) * 256 + c0];
    float4 a3 = *(const float4*)&aw1[(size_t)(kc + 3) * 256 + c0];
#pragma unroll
    for (int q = 0; q < QB; q++)
#pragma unroll
      for (int j = 0; j < 5; j++) {
        float4 iv = *(float4*)&s_inp[q * KNB + nb0 + j][kc];
        acc[q][j][0] += iv.x * a0.x + iv.y * a1.x + iv.z * a2.x + iv.w * a3.x;
        acc[q][j][1] += iv.x * a0.y + iv.y * a1.y + iv.z * a2.y + iv.w * a3.y;
        acc[q][j][2] += iv.x * a0.z + iv.y * a1.z + iv.z * a2.z + iv.w * a3.z;
        acc[q][j][3] += iv.x * a0.w + iv.y * a1.w + iv.z * a2.w + iv.w * a3.w;
      }
  }

  // epilogue: relu(+ab1) . aw2, butterfly-reduce 64 lanes -> sim
  float4 b1 = *(const float4*)&ab1[c0];
  float4 w2 = *(const float4*)&aw2[c0];
  float ab2v = ab2[0];
#pragma unroll
  for (int q = 0; q < QB; q++)
#pragma unroll
    for (int j = 0; j < 5; j++) {
      float s = fmaxf(acc[q][j][0] + b1.x, 0.f) * w2.x +
                fmaxf(acc[q][j][1] + b1.y, 0.f) * w2.y +
                fmaxf(acc[q][j][2] + b1.z, 0.f) * w2.z +
                fmaxf(acc[q][j][3] + b1.w, 0.f) * w2.w;
#pragma unroll
      for (int off = 32; off > 0; off >>= 1) s += __shfl_xor(s, off);
      if (lane == 0) s_sim[q * KNB + nb0 + j] = s + ab2v;
    }
  __syncthreads();

  // C: softmax over K=20, out = sum attn * (v_gather + rpe)
  {
    int q = tid >> 6, c = tid & 63;
    float mx = -3.402823466e38f;
#pragma unroll
    for (int n = 0; n < KNB; n++) mx = fmaxf(mx, s_sim[q * KNB + n]);
    float e[KNB];
    float sum = 0.f;
#pragma unroll
    for (int n = 0; n < KNB; n++) {
      e[n] = expf(s_sim[q * KNB + n] - mx);
      sum += e[n];
    }
    float inv = 1.f / sum;
    float o = 0.f;
#pragma unroll
    for (int n = 0; n < KNB; n++) {
      int g = s_nb[q * KNB + n];
      float vnb = qkv[(size_t)g * 192 + 128 + c] + s_inp[q * KNB + n][64 + c];
      o += (e[n] * inv) * vnb;
    }
    xout[(size_t)(i0 + q) * 64 + c] = o;
  }
}

// ---------------------------------------------------------------------------
// K5: global max-pool + fc1 + fc3 (unchanged)
// ---------------------------------------------------------------------------
__global__ __launch_bounds__(256) void k_final(const float* __restrict__ x,
                                               const float* __restrict__ fc1w,
                                               const float* __restrict__ fc1b,
                                               const float* __restrict__ fc3w,
                                               const float* __restrict__ fc3b,
                                               float* __restrict__ out) {
  __shared__ float red[4][64];
  __shared__ float m[64];
  __shared__ float h1[32];
  int b = blockIdx.x;
  int tid = threadIdx.x;
  int c = tid & 63, pg = tid >> 6;
  float mx = -3.402823466e38f;
  for (int p = pg; p < NPTS; p += 4)
    mx = fmaxf(mx, x[((size_t)b * NPTS + p) * 64 + c]);
  red[pg][c] = mx;
  __syncthreads();
  if (tid < 64)
    m[c] = fmaxf(fmaxf(red[0][c], red[1][c]), fmaxf(red[2][c], red[3][c]));
  __syncthreads();
  if (tid < 32) {
    float a = fc1b[tid];
#pragma unroll 8
    for (int k = 0; k < 64; k++) a += m[k] * fc1w[k * 32 + tid];
    h1[tid] = fmaxf(a, 0.f);
  }
  __syncthreads();
  if (tid < 3) {
    float a = fc3b[tid];
#pragma unroll
    for (int k = 0; k < 32; k++) a += h1[k] * fc3w[k * 3 + tid];
    out[b * 3 + tid] = a;
  }
}

// ---------------------------------------------------------------------------
extern "C" void kernel_launch(void* const* d_in, const int* in_sizes, int n_in,
                              void* d_out, int out_size, void* d_ws,
                              size_t ws_size, hipStream_t stream) {
  const float* pts    = (const float*)d_in[0];
  const float* conv_w = (const float*)d_in[1];
  const float* conv_b = (const float*)d_in[2];
  const float* fc1w = (const float*)d_in[21];
  const float* fc1b = (const float*)d_in[22];
  const float* fc3w = (const float*)d_in[23];
  const float* fc3b = (const float*)d_in[24];
  float* outp = (float*)d_out;

  char* ws = (char*)d_ws;
  float*  x0   = (float*) (ws);
  int*    idx  = (int*)   (ws + (size_t)4 * 1048576);
  float2* part = (float2*)(ws + (size_t)6 * 1048576);
  float*  qkv  = (float*) (ws + (size_t)6 * 1048576);   // reuses part region
  float*  x1   = (float*) (ws + (size_t)19 * 1048576);
  float*  x2   = (float*) (ws + (size_t)19 * 1048576 + 4194304);

  k_conv<<<(TOTAL * 64 + 255) / 256, 256, 0, stream>>>(pts, conv_w, conv_b, x0);
  k_knn_part<<<dim3(TOTAL / 256, SPLITS), 256, 0, stream>>>(pts, part);
  k_knn_merge<<<TOTAL / 32, 256, 0, stream>>>(part, idx);

  // layer 1
  {
    const float* qkvw = (const float*)d_in[3];
    k_qkv<<<(TOTAL * 192 + 255) / 256, 256, 0, stream>>>(x0, qkvw, qkv);
    k_attn<<<TOTAL / QB, 256, 0, stream>>>(
        pts, qkv, idx, (const float*)d_in[4], (const float*)d_in[5],
        (const float*)d_in[6], (const float*)d_in[7], (const float*)d_in[8],
        (const float*)d_in[9], (const float*)d_in[10], (const float*)d_in[11],
        x1);
  }
  // layer 2
  {
    const float* qkvw = (const float*)d_in[12];
    k_qkv<<<(TOTAL * 192 + 255) / 256, 256, 0, stream>>>(x1, qkvw, qkv);
    k_attn<<<TOTAL / QB, 256, 0, stream>>>(
        pts, qkv, idx, (const float*)d_in[13], (const float*)d_in[14],
        (const float*)d_in[15], (const float*)d_in[16], (const float*)d_in[17],
        (const float*)d_in[18], (const float*)d_in[19], (const float*)d_in[20],
        x2);
  }
  k_final<<<BATCH, 256, 0, stream>>>(x2, fc1w, fc1b, fc3w, fc3b, outp);
}

// Round 6
// 2183.310 us; speedup vs baseline: 2.3151x; 1.6502x over previous
//
#include <hip/hip_runtime.h>
#include <cstdint>
#include <cstddef>

#define KNB 20
#define NPTS 8192
#define BATCH 2
#define TOTAL (BATCH * NPTS)
#define SPLITS 8
#define CPS (NPTS / SPLITS)   // 1024 candidates per split
#define QB 4                  // queries per attention block

// ---------------------------------------------------------------------------
// K1: pointwise conv 3->64 + relu
// ---------------------------------------------------------------------------
__global__ __launch_bounds__(256) void k_conv(const float* __restrict__ pts,
                                              const float* __restrict__ w,
                                              const float* __restrict__ b,
                                              float* __restrict__ x0) {
  int gid = blockIdx.x * 256 + threadIdx.x;
  if (gid >= TOTAL * 64) return;
  int p = gid >> 6, c = gid & 63;
  float px = pts[p * 3 + 0], py = pts[p * 3 + 1], pz = pts[p * 3 + 2];
  float acc = b[c] + px * w[c] + py * w[64 + c] + pz * w[128 + c];
  x0[gid] = fmaxf(acc, 0.f);
}

// ---------------------------------------------------------------------------
// K2a: partial KNN (unchanged — bit-exact vs lax.top_k).
// ---------------------------------------------------------------------------
__global__ __launch_bounds__(256) void k_knn_part(const float* __restrict__ pts,
                                                  float2* __restrict__ part) {
  __shared__ float sx[CPS], sy[CPS], sz[CPS];
  int tid = threadIdx.x;
  int qb = blockIdx.x;
  int s = blockIdx.y;
  int q = qb * 256 + tid;
  int b = q >> 13;
  const float* pbase = pts + (size_t)b * NPTS * 3;
  const float* cbase = pbase + (size_t)s * CPS * 3;

  for (int c = tid; c < CPS; c += 256) {
    sx[c] = cbase[c * 3 + 0];
    sy[c] = cbase[c * 3 + 1];
    sz[c] = cbase[c * 3 + 2];
  }
  float qx = pts[q * 3 + 0], qy = pts[q * 3 + 1], qz = pts[q * 3 + 2];
  __syncthreads();

  float dist[KNB];
  int id[KNB];
#pragma unroll
  for (int j = 0; j < KNB; j++) { dist[j] = 3.402823466e38f; id[j] = 0; }

  int cid0 = s * CPS;
  for (int c = 0; c < CPS; c++) {
    float dx = qx - sx[c];
    float dy = qy - sy[c];
    float dz = qz - sz[c];
    float d2 = dx * dx + dy * dy + dz * dz;
    if (d2 < dist[KNB - 1]) {
      int cid = cid0 + c;
#pragma unroll
      for (int j = KNB - 1; j >= 0; j--) {
        bool cj = d2 < dist[j];
        bool cjm1 = (j > 0) && (d2 < dist[j - 1]);
        if (cj) {
          dist[j] = cjm1 ? dist[j - 1] : d2;
          id[j]   = cjm1 ? id[j - 1]   : cid;
        }
      }
    }
  }

  float2* dst = part + ((size_t)q * SPLITS + s) * KNB;
#pragma unroll
  for (int j = 0; j < KNB; j++)
    dst[j] = make_float2(dist[j], __int_as_float(id[j]));
}

// ---------------------------------------------------------------------------
// K2b: merge 8 sorted lists of 20 -> top-20 (unchanged).
// ---------------------------------------------------------------------------
__global__ __launch_bounds__(256) void k_knn_merge(const float2* __restrict__ part,
                                                   int* __restrict__ idxbuf) {
  __shared__ float sd[32][SPLITS][KNB];
  __shared__ int   si[32][SPLITS][KNB];
  __shared__ int   sp[32][SPLITS];
  int tid = threadIdx.x;
  int lq = tid >> 3, s = tid & 7;
  int q = blockIdx.x * 32 + lq;

  const float2* src = part + ((size_t)q * SPLITS + s) * KNB;
#pragma unroll
  for (int j = 0; j < KNB; j++) {
    float2 v = src[j];
    sd[lq][s][j] = v.x;
    si[lq][s][j] = __float_as_int(v.y);
  }
  sp[lq][s] = 0;
  __syncthreads();

  if (s == 0) {
    int bq = q >> 13;
    for (int step = 0; step < KNB; step++) {
      float best = 3.402823466e38f;
      int bs = 0, bi = 0;
      for (int s2 = 0; s2 < SPLITS; s2++) {
        int p = sp[lq][s2];
        float d = sd[lq][s2][p];
        if (d < best) { best = d; bs = s2; bi = si[lq][s2][p]; }
      }
      sp[lq][bs]++;
      idxbuf[q * KNB + step] = bq * NPTS + bi;
    }
  }
}

// ---------------------------------------------------------------------------
// K3: qkv GEMM (TOTAL,64) @ (64,192)
// ---------------------------------------------------------------------------
__global__ __launch_bounds__(256) void k_qkv(const float* __restrict__ x,
                                             const float* __restrict__ w,
                                             float* __restrict__ qkv) {
  int gid = blockIdx.x * 256 + threadIdx.x;
  if (gid >= TOTAL * 192) return;
  int p = gid / 192, c = gid % 192;
  const float* xr = x + (size_t)p * 64;
  float acc = 0.f;
#pragma unroll 16
  for (int k = 0; k < 64; k++) acc += xr[k] * w[k * 192 + c];
  qkv[gid] = acc;
}

// ---------------------------------------------------------------------------
// K4: fused attention, QB=4 queries/block, BARRIER-FREE phase B.
//  - aw1 read directly from global (131KB, L1/L2-resident). No phase-B
//    __syncthreads.
//  - t1 staged in-place in s_inp[row][0:64]; rpe -> [64:128]; then [0:64]
//    overwritten with q-k. LDS = 41.7KB -> 3 blocks/CU.
//  - NO min-waves launch-bounds arg: R5's __launch_bounds__(256,3) made the
//    allocator clamp to 84 VGPR (≈512/6) -> 80 accumulators spilled to
//    scratch -> 4.1 GB/dispatch HBM traffic. Bare (256) gave 132 VGPR and
//    zero spill in R3. Phase B needs ~140 live VGPRs; 3 waves/SIMD needs
//    ≤170. Let the allocator float.
// ---------------------------------------------------------------------------
__global__ __launch_bounds__(256) void k_attn(
    const float* __restrict__ pos, const float* __restrict__ qkv,
    const int* __restrict__ idxbuf,
    const float* __restrict__ pw1, const float* __restrict__ pb1,
    const float* __restrict__ pw2, const float* __restrict__ pb2,
    const float* __restrict__ aw1, const float* __restrict__ ab1,
    const float* __restrict__ aw2, const float* __restrict__ ab2,
    float* __restrict__ xout) {
  __shared__ float s_inp[QB * KNB][128];   // 40 KB  [row=q*20+n][c]
  __shared__ float s_qi[QB][64];
  __shared__ float s_sim[QB * KNB];
  __shared__ int   s_nb[QB * KNB];

  int i0 = blockIdx.x * QB;
  int tid = threadIdx.x;
  int lane = tid & 63;
  int wv = tid >> 6;
  int cA = tid & 63;          // fixed channel for phases A1/A2/A3

  {
    int q = tid >> 6, c = tid & 63;
    s_qi[q][c] = qkv[(size_t)(i0 + q) * 192 + c];
  }
  if (tid < QB * KNB) {
    int q = tid / KNB, n = tid % KNB;
    s_nb[q * KNB + n] = idxbuf[(i0 + q) * KNB + n];
  }
  __syncthreads();

  // A1: t1[row][h] = relu(rel . pw1[:,h] + pb1[h])  -> s_inp[row][0:64]
  {
    float w1x = pw1[cA], w1y = pw1[64 + cA], w1z = pw1[128 + cA];
    float b1h = pb1[cA];
#pragma unroll
    for (int j = 0; j < QB * KNB * 64 / 256; j++) {
      int it = tid + 256 * j;
      int row = it >> 6;
      int q = row / KNB;
      int g = s_nb[row];
      float rx = pos[(i0 + q) * 3 + 0] - pos[g * 3 + 0];
      float ry = pos[(i0 + q) * 3 + 1] - pos[g * 3 + 1];
      float rz = pos[(i0 + q) * 3 + 2] - pos[g * 3 + 2];
      float a = b1h + rx * w1x + ry * w1y + rz * w1z;
      s_inp[row][cA] = fmaxf(a, 0.f);
    }
  }
  __syncthreads();

  // A2: rpe[row][c] = t1[row] . pw2[:,c] + pb2[c] -> s_inp[row][64:128]
  //     pw2 read straight from global (L1-cached, coalesced across lanes).
  {
    float b2c = pb2[cA];
#pragma unroll
    for (int j = 0; j < QB * KNB * 64 / 256; j++) {
      int it = tid + 256 * j;
      int row = it >> 6;
      float acc = b2c;
      const float* t1r = &s_inp[row][0];
#pragma unroll 8
      for (int h = 0; h < 64; h++) acc += t1r[h] * pw2[h * 64 + cA];
      s_inp[row][64 + cA] = acc;
    }
  }
  __syncthreads();

  // A3: s_inp[row][0:64] = q - k_gather (overwrites t1; A2 reads are closed)
#pragma unroll
  for (int j = 0; j < QB * KNB * 64 / 256; j++) {
    int it = tid + 256 * j;
    int row = it >> 6;
    int q = row / KNB;
    int g = s_nb[row];
    float kv = qkv[(size_t)g * 192 + 64 + cA];
    s_inp[row][cA] = s_qi[q][cA] - kv;
  }
  __syncthreads();

  // B: hidden(80x256) = inp @ aw1 — aw1 straight from global, no barriers.
  int nb0 = 5 * wv;      // wave wv covers neighbors nb0..nb0+4 of EVERY query
  int c0 = 4 * lane;
  float acc[QB][5][4];
#pragma unroll
  for (int q = 0; q < QB; q++)
#pragma unroll
    for (int j = 0; j < 5; j++)
#pragma unroll
      for (int cc = 0; cc < 4; cc++) acc[q][j][cc] = 0.f;

#pragma unroll 2
  for (int kc = 0; kc < 128; kc += 4) {
    float4 a0 = *(const float4*)&aw1[(size_t)(kc + 0) * 256 + c0];
    float4 a1 = *(const float4*)&aw1[(size_t)(kc + 1) * 256 + c0];
    float4 a2 = *(const float4*)&aw1[(size_t)(kc + 2) * 256 + c0];
    float4 a3 = *(const float4*)&aw1[(size_t)(kc + 3) * 256 + c0];
#pragma unroll
    for (int q = 0; q < QB; q++)
#pragma unroll
      for (int j = 0; j < 5; j++) {
        float4 iv = *(float4*)&s_inp[q * KNB + nb0 + j][kc];
        acc[q][j][0] += iv.x * a0.x + iv.y * a1.x + iv.z * a2.x + iv.w * a3.x;
        acc[q][j][1] += iv.x * a0.y + iv.y * a1.y + iv.z * a2.y + iv.w * a3.y;
        acc[q][j][2] += iv.x * a0.z + iv.y * a1.z + iv.z * a2.z + iv.w * a3.z;
        acc[q][j][3] += iv.x * a0.w + iv.y * a1.w + iv.z * a2.w + iv.w * a3.w;
      }
  }

  // epilogue: relu(+ab1) . aw2, butterfly-reduce 64 lanes -> sim
  float4 b1 = *(const float4*)&ab1[c0];
  float4 w2 = *(const float4*)&aw2[c0];
  float ab2v = ab2[0];
#pragma unroll
  for (int q = 0; q < QB; q++)
#pragma unroll
    for (int j = 0; j < 5; j++) {
      float s = fmaxf(acc[q][j][0] + b1.x, 0.f) * w2.x +
                fmaxf(acc[q][j][1] + b1.y, 0.f) * w2.y +
                fmaxf(acc[q][j][2] + b1.z, 0.f) * w2.z +
                fmaxf(acc[q][j][3] + b1.w, 0.f) * w2.w;
#pragma unroll
      for (int off = 32; off > 0; off >>= 1) s += __shfl_xor(s, off);
      if (lane == 0) s_sim[q * KNB + nb0 + j] = s + ab2v;
    }
  __syncthreads();

  // C: softmax over K=20, out = sum attn * (v_gather + rpe)
  {
    int q = tid >> 6, c = tid & 63;
    float mx = -3.402823466e38f;
#pragma unroll
    for (int n = 0; n < KNB; n++) mx = fmaxf(mx, s_sim[q * KNB + n]);
    float e[KNB];
    float sum = 0.f;
#pragma unroll
    for (int n = 0; n < KNB; n++) {
      e[n] = expf(s_sim[q * KNB + n] - mx);
      sum += e[n];
    }
    float inv = 1.f / sum;
    float o = 0.f;
#pragma unroll
    for (int n = 0; n < KNB; n++) {
      int g = s_nb[q * KNB + n];
      float vnb = qkv[(size_t)g * 192 + 128 + c] + s_inp[q * KNB + n][64 + c];
      o += (e[n] * inv) * vnb;
    }
    xout[(size_t)(i0 + q) * 64 + c] = o;
  }
}

// ---------------------------------------------------------------------------
// K5: global max-pool + fc1 + fc3 (unchanged)
// ---------------------------------------------------------------------------
__global__ __launch_bounds__(256) void k_final(const float* __restrict__ x,
                                               const float* __restrict__ fc1w,
                                               const float* __restrict__ fc1b,
                                               const float* __restrict__ fc3w,
                                               const float* __restrict__ fc3b,
                                               float* __restrict__ out) {
  __shared__ float red[4][64];
  __shared__ float m[64];
  __shared__ float h1[32];
  int b = blockIdx.x;
  int tid = threadIdx.x;
  int c = tid & 63, pg = tid >> 6;
  float mx = -3.402823466e38f;
  for (int p = pg; p < NPTS; p += 4)
    mx = fmaxf(mx, x[((size_t)b * NPTS + p) * 64 + c]);
  red[pg][c] = mx;
  __syncthreads();
  if (tid < 64)
    m[c] = fmaxf(fmaxf(red[0][c], red[1][c]), fmaxf(red[2][c], red[3][c]));
  __syncthreads();
  if (tid < 32) {
    float a = fc1b[tid];
#pragma unroll 8
    for (int k = 0; k < 64; k++) a += m[k] * fc1w[k * 32 + tid];
    h1[tid] = fmaxf(a, 0.f);
  }
  __syncthreads();
  if (tid < 3) {
    float a = fc3b[tid];
#pragma unroll
    for (int k = 0; k < 32; k++) a += h1[k] * fc3w[k * 3 + tid];
    out[b * 3 + tid] = a;
  }
}

// ---------------------------------------------------------------------------
extern "C" void kernel_launch(void* const* d_in, const int* in_sizes, int n_in,
                              void* d_out, int out_size, void* d_ws,
                              size_t ws_size, hipStream_t stream) {
  const float* pts    = (const float*)d_in[0];
  const float* conv_w = (const float*)d_in[1];
  const float* conv_b = (const float*)d_in[2];
  const float* fc1w = (const float*)d_in[21];
  const float* fc1b = (const float*)d_in[22];
  const float* fc3w = (const float*)d_in[23];
  const float* fc3b = (const float*)d_in[24];
  float* outp = (float*)d_out;

  char* ws = (char*)d_ws;
  float*  x0   = (float*) (ws);
  int*    idx  = (int*)   (ws + (size_t)4 * 1048576);
  float2* part = (float2*)(ws + (size_t)6 * 1048576);
  float*  qkv  = (float*) (ws + (size_t)6 * 1048576);   // reuses part region
  float*  x1   = (float*) (ws + (size_t)19 * 1048576);
  float*  x2   = (float*) (ws + (size_t)19 * 1048576 + 4194304);

  k_conv<<<(TOTAL * 64 + 255) / 256, 256, 0, stream>>>(pts, conv_w, conv_b, x0);
  k_knn_part<<<dim3(TOTAL / 256, SPLITS), 256, 0, stream>>>(pts, part);
  k_knn_merge<<<TOTAL / 32, 256, 0, stream>>>(part, idx);

  // layer 1
  {
    const float* qkvw = (const float*)d_in[3];
    k_qkv<<<(TOTAL * 192 + 255) / 256, 256, 0, stream>>>(x0, qkvw, qkv);
    k_attn<<<TOTAL / QB, 256, 0, stream>>>(
        pts, qkv, idx, (const float*)d_in[4], (const float*)d_in[5],
        (const float*)d_in[6], (const float*)d_in[7], (const float*)d_in[8],
        (const float*)d_in[9], (const float*)d_in[10], (const float*)d_in[11],
        x1);
  }
  // layer 2
  {
    const float* qkvw = (const float*)d_in[12];
    k_qkv<<<(TOTAL * 192 + 255) / 256, 256, 0, stream>>>(x1, qkvw, qkv);
    k_attn<<<TOTAL / QB, 256, 0, stream>>>(
        pts, qkv, idx, (const float*)d_in[13], (const float*)d_in[14],
        (const float*)d_in[15], (const float*)d_in[16], (const float*)d_in[17],
        (const float*)d_in[18], (const float*)d_in[19], (const float*)d_in[20],
        x2);
  }
  k_final<<<BATCH, 256, 0, stream>>>(x2, fc1w, fc1b, fc3w, fc3b, outp);
}

// Round 8
// 1746.411 us; speedup vs baseline: 2.8943x; 1.2502x over previous
//
#include <hip/hip_runtime.h>
#include <cstdint>
#include <cstddef>

#define KNB 20
#define NPTS 8192
#define BATCH 2
#define TOTAL (BATCH * NPTS)
#define QB 4                  // queries per attention block

// ---------------------------------------------------------------------------
// K1: pointwise conv 3->64 + relu
// ---------------------------------------------------------------------------
__global__ __launch_bounds__(256) void k_conv(const float* __restrict__ pts,
                                              const float* __restrict__ w,
                                              const float* __restrict__ b,
                                              float* __restrict__ x0) {
  int gid = blockIdx.x * 256 + threadIdx.x;
  if (gid >= TOTAL * 64) return;
  int p = gid >> 6, c = gid & 63;
  float px = pts[p * 3 + 0], py = pts[p * 3 + 1], pz = pts[p * 3 + 2];
  float acc = b[c] + px * w[c] + py * w[64 + c] + pz * w[128 + c];
  x0[gid] = fmaxf(acc, 0.f);
}

// ---------------------------------------------------------------------------
// K2: KNN, one WAVE per query. 64 lanes split the 8192 candidates (128 each,
// strided by 64 within LDS tiles of 1024). Per-lane exact top-20 via
// branchless sorted insert (strict <, ascending cid per lane). Cross-lane
// merge: 20x min-extract on packed (d2bits<<32|cid) u64 — reproduces
// lax.top_k (d2 asc, index asc) ordering exactly.
// d2 computed with __fmul_rn/__fadd_rn: numpy evaluates ((dx^2+dy^2)+dz^2)
// with every op separately rounded; barring FMA contraction makes our
// ranking bit-identical to the reference (no near-tie lottery).
// ---------------------------------------------------------------------------
__global__ __launch_bounds__(256) void k_knn(const float* __restrict__ pts,
                                             int* __restrict__ idxbuf) {
  __shared__ float sp[3 * 1024];   // 12 KB candidate tile (interleaved xyz)
  int tid = threadIdx.x;
  int wv = tid >> 6, lane = tid & 63;
  int q = blockIdx.x * 4 + wv;            // 4 queries/block, one per wave
  int bq = q >> 13;                       // block never straddles batch
  const float* pbase = pts + (size_t)bq * NPTS * 3;
  float qx = pts[q * 3 + 0], qy = pts[q * 3 + 1], qz = pts[q * 3 + 2];

  float dist[KNB];
  int id[KNB];
#pragma unroll
  for (int j = 0; j < KNB; j++) { dist[j] = 3.402823466e38f; id[j] = 0; }

  for (int tile = 0; tile < NPTS; tile += 1024) {
    __syncthreads();
    for (int t = tid; t < 3072; t += 256) sp[t] = pbase[tile * 3 + t];
    __syncthreads();
#pragma unroll 4
    for (int i = 0; i < 16; i++) {
      int c = lane + (i << 6);
      float dx = qx - sp[c * 3 + 0];
      float dy = qy - sp[c * 3 + 1];
      float dz = qz - sp[c * 3 + 2];
      float d2 = __fadd_rn(__fadd_rn(__fmul_rn(dx, dx), __fmul_rn(dy, dy)),
                           __fmul_rn(dz, dz));
      if (d2 < dist[KNB - 1]) {
        int cid = tile + c;
        // branchless sorted insert (ascending); strict < keeps lax.top_k
        // stable tie-breaking (earlier index wins) within a lane.
#pragma unroll
        for (int j = KNB - 1; j >= 0; j--) {
          bool cj = d2 < dist[j];
          bool cjm1 = (j > 0) && (d2 < dist[j - 1]);
          if (cj) {
            dist[j] = cjm1 ? dist[j - 1] : d2;
            id[j]   = cjm1 ? id[j - 1]   : cid;
          }
        }
      }
    }
  }

  // 20-step cross-lane merge: min over packed (d2bits, cid).
  int bqoff = bq * NPTS;
  for (int step = 0; step < KNB; step++) {
    unsigned long long p =
        ((unsigned long long)__float_as_uint(dist[0]) << 32) | (unsigned)id[0];
    unsigned long long m = p;
#pragma unroll
    for (int off = 32; off >= 1; off >>= 1) {
      unsigned long long o = __shfl_xor(m, off);
      m = (o < m) ? o : m;
    }
    if (lane == 0) idxbuf[q * KNB + step] = bqoff + (int)(m & 0xffffffffULL);
    if (p == m) {   // winning lane pops its head (static unrolled shift)
#pragma unroll
      for (int j = 0; j < KNB - 1; j++) { dist[j] = dist[j + 1]; id[j] = id[j + 1]; }
      dist[KNB - 1] = 3.402823466e38f;
    }
  }
}

// ---------------------------------------------------------------------------
// K3: qkv GEMM (TOTAL,64) @ (64,192)
// ---------------------------------------------------------------------------
__global__ __launch_bounds__(256) void k_qkv(const float* __restrict__ x,
                                             const float* __restrict__ w,
                                             float* __restrict__ qkv) {
  int gid = blockIdx.x * 256 + threadIdx.x;
  if (gid >= TOTAL * 192) return;
  int p = gid / 192, c = gid % 192;
  const float* xr = x + (size_t)p * 64;
  float acc = 0.f;
#pragma unroll 16
  for (int k = 0; k < 64; k++) acc += xr[k] * w[k * 192 + c];
  qkv[gid] = acc;
}

// ---------------------------------------------------------------------------
// K4: fused attention, QB=4 queries/block.
//  A2: pw2 staged 8 coefficients at a time in NAMED registers (64 global
//      loads/thread vs 1280), t1 rows read as b128. ALL twenty accumulators
//      init to pb2[cA] (R7 bug: only r0 got the bias -> absmax 4.15e-3).
//  B:  8 cols/lane via half-wave row split -> 10 b128/kc-step per wave:
//      LDS-pipe below VALU -> VALU-bound.
//  aw1/pw2 from global (L1/L2-hot); NO min-waves launch-bounds arg
//  (R5: (256,3) clamped to 84 VGPR -> 4.1 GB spill).
// ---------------------------------------------------------------------------
__global__ __launch_bounds__(256) void k_attn(
    const float* __restrict__ pos, const float* __restrict__ qkv,
    const int* __restrict__ idxbuf,
    const float* __restrict__ pw1, const float* __restrict__ pb1,
    const float* __restrict__ pw2, const float* __restrict__ pb2,
    const float* __restrict__ aw1, const float* __restrict__ ab1,
    const float* __restrict__ aw2, const float* __restrict__ ab2,
    float* __restrict__ xout) {
  __shared__ float s_inp[QB * KNB][128];   // 40 KB  [row=q*20+n][c]
  __shared__ float s_qi[QB][64];
  __shared__ float s_sim[QB * KNB];
  __shared__ int   s_nb[QB * KNB];

  int i0 = blockIdx.x * QB;
  int tid = threadIdx.x;
  int lane = tid & 63;
  int wv = tid >> 6;
  int cA = tid & 63;          // fixed channel for phases A1/A2/A3

  {
    int q = tid >> 6, c = tid & 63;
    s_qi[q][c] = qkv[(size_t)(i0 + q) * 192 + c];
  }
  if (tid < QB * KNB) {
    int q = tid / KNB, n = tid % KNB;
    s_nb[q * KNB + n] = idxbuf[(i0 + q) * KNB + n];
  }
  __syncthreads();

  // A1: t1[row][h] = relu(rel . pw1[:,h] + pb1[h])  -> s_inp[row][0:64]
  //     thread handles rows wv+4j, channel cA.
  {
    float w1x = pw1[cA], w1y = pw1[64 + cA], w1z = pw1[128 + cA];
    float b1h = pb1[cA];
#pragma unroll
    for (int j = 0; j < KNB; j++) {
      int row = wv + 4 * j;
      int q = row / KNB;
      int g = s_nb[row];
      float rx = pos[(i0 + q) * 3 + 0] - pos[g * 3 + 0];
      float ry = pos[(i0 + q) * 3 + 1] - pos[g * 3 + 1];
      float rz = pos[(i0 + q) * 3 + 2] - pos[g * 3 + 2];
      float a = b1h + rx * w1x + ry * w1y + rz * w1z;
      s_inp[row][cA] = fmaxf(a, 0.f);
    }
  }
  __syncthreads();

  // A2: rpe[row][cA] = t1[row] . pw2[:,cA] + pb2[cA] -> s_inp[row][64:128]
  //     h tiled by 8: pw2 coeffs live in named registers, reused over 20 rows.
  {
    float b2c = pb2[cA];
    float r0 = b2c, r1 = b2c, r2 = b2c, r3 = b2c, r4 = b2c;
    float r5 = b2c, r6 = b2c, r7 = b2c, r8 = b2c, r9 = b2c;
    float r10 = b2c, r11 = b2c, r12 = b2c, r13 = b2c, r14 = b2c;
    float r15 = b2c, r16 = b2c, r17 = b2c, r18 = b2c, r19 = b2c;
#pragma unroll
    for (int h8 = 0; h8 < 64; h8 += 8) {
      float w0 = pw2[(h8 + 0) * 64 + cA];
      float w1 = pw2[(h8 + 1) * 64 + cA];
      float w2 = pw2[(h8 + 2) * 64 + cA];
      float w3 = pw2[(h8 + 3) * 64 + cA];
      float w4 = pw2[(h8 + 4) * 64 + cA];
      float w5 = pw2[(h8 + 5) * 64 + cA];
      float w6 = pw2[(h8 + 6) * 64 + cA];
      float w7 = pw2[(h8 + 7) * 64 + cA];
#define A2ROW(J, R)                                                          \
      {                                                                      \
        float4 ta = *(float4*)&s_inp[wv + 4 * (J)][h8];                      \
        float4 tb = *(float4*)&s_inp[wv + 4 * (J)][h8 + 4];                  \
        R += ta.x * w0 + ta.y * w1 + ta.z * w2 + ta.w * w3 +                 \
             tb.x * w4 + tb.y * w5 + tb.z * w6 + tb.w * w7;                  \
      }
      A2ROW(0, r0)  A2ROW(1, r1)  A2ROW(2, r2)  A2ROW(3, r3)  A2ROW(4, r4)
      A2ROW(5, r5)  A2ROW(6, r6)  A2ROW(7, r7)  A2ROW(8, r8)  A2ROW(9, r9)
      A2ROW(10, r10) A2ROW(11, r11) A2ROW(12, r12) A2ROW(13, r13)
      A2ROW(14, r14) A2ROW(15, r15) A2ROW(16, r16) A2ROW(17, r17)
      A2ROW(18, r18) A2ROW(19, r19)
#undef A2ROW
    }
    s_inp[wv + 0][64 + cA] = r0;   s_inp[wv + 4][64 + cA] = r1;
    s_inp[wv + 8][64 + cA] = r2;   s_inp[wv + 12][64 + cA] = r3;
    s_inp[wv + 16][64 + cA] = r4;  s_inp[wv + 20][64 + cA] = r5;
    s_inp[wv + 24][64 + cA] = r6;  s_inp[wv + 28][64 + cA] = r7;
    s_inp[wv + 32][64 + cA] = r8;  s_inp[wv + 36][64 + cA] = r9;
    s_inp[wv + 40][64 + cA] = r10; s_inp[wv + 44][64 + cA] = r11;
    s_inp[wv + 48][64 + cA] = r12; s_inp[wv + 52][64 + cA] = r13;
    s_inp[wv + 56][64 + cA] = r14; s_inp[wv + 60][64 + cA] = r15;
    s_inp[wv + 64][64 + cA] = r16; s_inp[wv + 68][64 + cA] = r17;
    s_inp[wv + 72][64 + cA] = r18; s_inp[wv + 76][64 + cA] = r19;
  }
  __syncthreads();

  // A3: s_inp[row][0:64] = q - k_gather (overwrites t1; A2 reads are closed)
#pragma unroll
  for (int j = 0; j < KNB; j++) {
    int row = wv + 4 * j;
    int q = row / KNB;
    int g = s_nb[row];
    float kv = qkv[(size_t)g * 192 + 64 + cA];
    s_inp[row][cA] = s_qi[q][cA] - kv;
  }
  __syncthreads();

  // B: hidden(80x256) = inp @ aw1. Half-wave split: lanes 0-31 -> q{0,1},
  // lanes 32-63 -> q{2,3}; 8 cols/lane. 10 b128 + 320 FMA per kc-step.
  int half = lane >> 5;
  int li = lane & 31;
  int col0 = li * 8;
  int nb0 = 5 * wv;
  float acc[2][5][8];
#pragma unroll
  for (int qq = 0; qq < 2; qq++)
#pragma unroll
    for (int j = 0; j < 5; j++)
#pragma unroll
      for (int cc = 0; cc < 8; cc++) acc[qq][j][cc] = 0.f;

  for (int kc = 0; kc < 128; kc += 4) {
    float4 wA[4], wB[4];
#pragma unroll
    for (int r = 0; r < 4; r++) {
      wA[r] = *(const float4*)&aw1[(size_t)(kc + r) * 256 + col0];
      wB[r] = *(const float4*)&aw1[(size_t)(kc + r) * 256 + col0 + 4];
    }
#pragma unroll
    for (int qq = 0; qq < 2; qq++) {
      int rowb = (half * 2 + qq) * KNB + nb0;
#pragma unroll
      for (int j = 0; j < 5; j++) {
        float4 iv = *(float4*)&s_inp[rowb + j][kc];
        acc[qq][j][0] += iv.x*wA[0].x + iv.y*wA[1].x + iv.z*wA[2].x + iv.w*wA[3].x;
        acc[qq][j][1] += iv.x*wA[0].y + iv.y*wA[1].y + iv.z*wA[2].y + iv.w*wA[3].y;
        acc[qq][j][2] += iv.x*wA[0].z + iv.y*wA[1].z + iv.z*wA[2].z + iv.w*wA[3].z;
        acc[qq][j][3] += iv.x*wA[0].w + iv.y*wA[1].w + iv.z*wA[2].w + iv.w*wA[3].w;
        acc[qq][j][4] += iv.x*wB[0].x + iv.y*wB[1].x + iv.z*wB[2].x + iv.w*wB[3].x;
        acc[qq][j][5] += iv.x*wB[0].y + iv.y*wB[1].y + iv.z*wB[2].y + iv.w*wB[3].y;
        acc[qq][j][6] += iv.x*wB[0].z + iv.y*wB[1].z + iv.z*wB[2].z + iv.w*wB[3].z;
        acc[qq][j][7] += iv.x*wB[0].w + iv.y*wB[1].w + iv.z*wB[2].w + iv.w*wB[3].w;
      }
    }
  }

  // epilogue: relu(+ab1) . aw2 over 8 cols, reduce across 32 lanes (li).
  float4 b1A = *(const float4*)&ab1[col0];
  float4 b1B = *(const float4*)&ab1[col0 + 4];
  float4 w2A = *(const float4*)&aw2[col0];
  float4 w2B = *(const float4*)&aw2[col0 + 4];
  float ab2v = ab2[0];
#pragma unroll
  for (int qq = 0; qq < 2; qq++)
#pragma unroll
    for (int j = 0; j < 5; j++) {
      float s = fmaxf(acc[qq][j][0] + b1A.x, 0.f) * w2A.x +
                fmaxf(acc[qq][j][1] + b1A.y, 0.f) * w2A.y +
                fmaxf(acc[qq][j][2] + b1A.z, 0.f) * w2A.z +
                fmaxf(acc[qq][j][3] + b1A.w, 0.f) * w2A.w +
                fmaxf(acc[qq][j][4] + b1B.x, 0.f) * w2B.x +
                fmaxf(acc[qq][j][5] + b1B.y, 0.f) * w2B.y +
                fmaxf(acc[qq][j][6] + b1B.z, 0.f) * w2B.z +
                fmaxf(acc[qq][j][7] + b1B.w, 0.f) * w2B.w;
#pragma unroll
      for (int off = 16; off >= 1; off >>= 1) s += __shfl_xor(s, off);
      if (li == 0) s_sim[(half * 2 + qq) * KNB + nb0 + j] = s + ab2v;
    }
  __syncthreads();

  // C: softmax over K=20, out = sum attn * (v_gather + rpe)
  {
    int q = tid >> 6, c = tid & 63;
    float mx = -3.402823466e38f;
#pragma unroll
    for (int n = 0; n < KNB; n++) mx = fmaxf(mx, s_sim[q * KNB + n]);
    float e[KNB];
    float sum = 0.f;
#pragma unroll
    for (int n = 0; n < KNB; n++) {
      e[n] = expf(s_sim[q * KNB + n] - mx);
      sum += e[n];
    }
    float inv = 1.f / sum;
    float o = 0.f;
#pragma unroll
    for (int n = 0; n < KNB; n++) {
      int g = s_nb[q * KNB + n];
      float vnb = qkv[(size_t)g * 192 + 128 + c] + s_inp[q * KNB + n][64 + c];
      o += (e[n] * inv) * vnb;
    }
    xout[(size_t)(i0 + q) * 64 + c] = o;
  }
}

// ---------------------------------------------------------------------------
// K5: global max-pool + fc1 + fc3 (unchanged)
// ---------------------------------------------------------------------------
__global__ __launch_bounds__(256) void k_final(const float* __restrict__ x,
                                               const float* __restrict__ fc1w,
                                               const float* __restrict__ fc1b,
                                               const float* __restrict__ fc3w,
                                               const float* __restrict__ fc3b,
                                               float* __restrict__ out) {
  __shared__ float red[4][64];
  __shared__ float m[64];
  __shared__ float h1[32];
  int b = blockIdx.x;
  int tid = threadIdx.x;
  int c = tid & 63, pg = tid >> 6;
  float mx = -3.402823466e38f;
  for (int p = pg; p < NPTS; p += 4)
    mx = fmaxf(mx, x[((size_t)b * NPTS + p) * 64 + c]);
  red[pg][c] = mx;
  __syncthreads();
  if (tid < 64)
    m[c] = fmaxf(fmaxf(red[0][c], red[1][c]), fmaxf(red[2][c], red[3][c]));
  __syncthreads();
  if (tid < 32) {
    float a = fc1b[tid];
#pragma unroll 8
    for (int k = 0; k < 64; k++) a += m[k] * fc1w[k * 32 + tid];
    h1[tid] = fmaxf(a, 0.f);
  }
  __syncthreads();
  if (tid < 3) {
    float a = fc3b[tid];
#pragma unroll
    for (int k = 0; k < 32; k++) a += h1[k] * fc3w[k * 3 + tid];
    out[b * 3 + tid] = a;
  }
}

// ---------------------------------------------------------------------------
// Workspace: x0 @0 (4MB) | idx @4MB (1.3MB) | qkv @6MB (12.6MB)
//            x1 @19MB (4.2MB) | x2 @23.2MB (4.2MB)
// ---------------------------------------------------------------------------
extern "C" void kernel_launch(void* const* d_in, const int* in_sizes, int n_in,
                              void* d_out, int out_size, void* d_ws,
                              size_t ws_size, hipStream_t stream) {
  const float* pts    = (const float*)d_in[0];
  const float* conv_w = (const float*)d_in[1];
  const float* conv_b = (const float*)d_in[2];
  const float* fc1w = (const float*)d_in[21];
  const float* fc1b = (const float*)d_in[22];
  const float* fc3w = (const float*)d_in[23];
  const float* fc3b = (const float*)d_in[24];
  float* outp = (float*)d_out;

  char* ws = (char*)d_ws;
  float* x0  = (float*)(ws);
  int*   idx = (int*)  (ws + (size_t)4 * 1048576);
  float* qkv = (float*)(ws + (size_t)6 * 1048576);
  float* x1  = (float*)(ws + (size_t)19 * 1048576);
  float* x2  = (float*)(ws + (size_t)19 * 1048576 + 4194304);

  k_conv<<<(TOTAL * 64 + 255) / 256, 256, 0, stream>>>(pts, conv_w, conv_b, x0);
  k_knn<<<TOTAL / 4, 256, 0, stream>>>(pts, idx);

  // layer 1
  {
    const float* qkvw = (const float*)d_in[3];
    k_qkv<<<(TOTAL * 192 + 255) / 256, 256, 0, stream>>>(x0, qkvw, qkv);
    k_attn<<<TOTAL / QB, 256, 0, stream>>>(
        pts, qkv, idx, (const float*)d_in[4], (const float*)d_in[5],
        (const float*)d_in[6], (const float*)d_in[7], (const float*)d_in[8],
        (const float*)d_in[9], (const float*)d_in[10], (const float*)d_in[11],
        x1);
  }
  // layer 2
  {
    const float* qkvw = (const float*)d_in[12];
    k_qkv<<<(TOTAL * 192 + 255) / 256, 256, 0, stream>>>(x1, qkvw, qkv);
    k_attn<<<TOTAL / QB, 256, 0, stream>>>(
        pts, qkv, idx, (const float*)d_in[13], (const float*)d_in[14],
        (const float*)d_in[15], (const float*)d_in[16], (const float*)d_in[17],
        (const float*)d_in[18], (const float*)d_in[19], (const float*)d_in[20],
        x2);
  }
  k_final<<<BATCH, 256, 0, stream>>>(x2, fc1w, fc1b, fc3w, fc3b, outp);
}

// Round 11
// 1699.487 us; speedup vs baseline: 2.9742x; 1.0276x over previous
//
#include <hip/hip_runtime.h>
#include <cstdint>
#include <cstddef>

#define KNB 20
#define NPTS 8192
#define BATCH 2
#define TOTAL (BATCH * NPTS)

// ---------------------------------------------------------------------------
// K1: pointwise conv 3->64 + relu
// ---------------------------------------------------------------------------
__global__ __launch_bounds__(256) void k_conv(const float* __restrict__ pts,
                                              const float* __restrict__ w,
                                              const float* __restrict__ b,
                                              float* __restrict__ x0) {
  int gid = blockIdx.x * 256 + threadIdx.x;
  if (gid >= TOTAL * 64) return;
  int p = gid >> 6, c = gid & 63;
  float px = pts[p * 3 + 0], py = pts[p * 3 + 1], pz = pts[p * 3 + 2];
  float acc = b[c] + px * w[c] + py * w[64 + c] + pz * w[128 + c];
  x0[gid] = fmaxf(acc, 0.f);
}

// ---------------------------------------------------------------------------
// K2: KNN, one WAVE per query, with a wave-global tau filter.
// Per tile: cross-lane bitonic sort of the 64 lane-heads (packed u64
// (d2bits<<32)|cid); tau = 20th smallest. tau >= wave's true 20th-best
// (20 smallest heads are 20 real elements), so skipping d2 > tau is EXACT.
// Candidates with d2 <= tau still go through the exact lane-local insert.
// d2 via __fmul_rn/__fadd_rn: bit-identical to numpy's ((dx²+dy²)+dz²).
// ---------------------------------------------------------------------------
__global__ __launch_bounds__(256) void k_knn(const float* __restrict__ pts,
                                             int* __restrict__ idxbuf) {
  __shared__ float sp[3 * 1024];   // 12 KB candidate tile
  int tid = threadIdx.x;
  int wv = tid >> 6, lane = tid & 63;
  int q = blockIdx.x * 4 + wv;            // 4 queries/block, one per wave
  int bq = q >> 13;                       // block never straddles batch
  const float* pbase = pts + (size_t)bq * NPTS * 3;
  float qx = pts[q * 3 + 0], qy = pts[q * 3 + 1], qz = pts[q * 3 + 2];

  float dist[KNB];
  int id[KNB];
#pragma unroll
  for (int j = 0; j < KNB; j++) { dist[j] = 3.402823466e38f; id[j] = 0; }
  float tau = 3.402823466e38f;

  for (int tile = 0; tile < NPTS; tile += 1024) {
    __syncthreads();
    for (int t = tid; t < 3072; t += 256) sp[t] = pbase[tile * 3 + t];
    __syncthreads();

    if (tile) {
      // refresh tau = 20th smallest of the 64 lane-heads (ascending bitonic).
      unsigned long long h =
          ((unsigned long long)__float_as_uint(dist[0]) << 32) | (unsigned)id[0];
#pragma unroll
      for (int k = 2; k <= 64; k <<= 1) {
#pragma unroll
        for (int j = k >> 1; j > 0; j >>= 1) {
          unsigned long long o = __shfl_xor(h, j);
          bool up = ((lane & k) == 0);
          bool lower = ((lane & j) == 0);
          bool takeMin = (up == lower);
          bool lt = h < o;
          h = (takeMin == lt) ? h : o;
        }
      }
      tau = __uint_as_float((unsigned)(__shfl(h, 19) >> 32));
    }

#pragma unroll 4
    for (int i = 0; i < 16; i++) {
      int c = lane + (i << 6);
      float dx = qx - sp[c * 3 + 0];
      float dy = qy - sp[c * 3 + 1];
      float dz = qz - sp[c * 3 + 2];
      float d2 = __fadd_rn(__fadd_rn(__fmul_rn(dx, dx), __fmul_rn(dy, dy)),
                           __fmul_rn(dz, dz));
      if (d2 <= tau && d2 < dist[KNB - 1]) {
        int cid = tile + c;
        // branchless sorted insert (ascending); strict < keeps lax.top_k
        // stable tie-breaking within a lane.
#pragma unroll
        for (int j = KNB - 1; j >= 0; j--) {
          bool cj = d2 < dist[j];
          bool cjm1 = (j > 0) && (d2 < dist[j - 1]);
          if (cj) {
            dist[j] = cjm1 ? dist[j - 1] : d2;
            id[j]   = cjm1 ? id[j - 1]   : cid;
          }
        }
      }
    }
  }

  // 20-step cross-lane merge: min over packed (d2bits, cid) — exact
  // lax.top_k order (d2 asc, index asc). Packed values are unique (each
  // lane holds >=20 real candidates with distinct cids), so exactly one
  // lane pops per step.
  int bqoff = bq * NPTS;
  for (int step = 0; step < KNB; step++) {
    unsigned long long p =
        ((unsigned long long)__float_as_uint(dist[0]) << 32) | (unsigned)id[0];
    unsigned long long m = p;
#pragma unroll
    for (int off = 32; off >= 1; off >>= 1) {
      unsigned long long o = __shfl_xor(m, off);
      m = (o < m) ? o : m;
    }
    if (lane == 0) idxbuf[q * KNB + step] = bqoff + (int)(m & 0xffffffffULL);
    if (p == m) {
#pragma unroll
      for (int j = 0; j < KNB - 1; j++) { dist[j] = dist[j + 1]; id[j] = id[j + 1]; }
      dist[KNB - 1] = 3.402823466e38f;
    }
  }
}

// ---------------------------------------------------------------------------
// K3: qkv GEMM (TOTAL,64) @ (64,192) — float4 outputs per thread.
// ---------------------------------------------------------------------------
__global__ __launch_bounds__(256) void k_qkv(const float* __restrict__ x,
                                             const float* __restrict__ w,
                                             float* __restrict__ qkv) {
  int gid = blockIdx.x * 256 + threadIdx.x;
  if (gid >= TOTAL * 48) return;
  int p = gid / 48, c4 = (gid % 48) * 4;
  const float* xr = x + (size_t)p * 64;
  float4 a = make_float4(0.f, 0.f, 0.f, 0.f);
#pragma unroll 8
  for (int k = 0; k < 64; k++) {
    float xv = xr[k];
    float4 wv = *(const float4*)&w[k * 192 + c4];
    a.x += xv * wv.x; a.y += xv * wv.y; a.z += xv * wv.z; a.w += xv * wv.w;
  }
  *(float4*)&qkv[(size_t)p * 192 + c4] = a;
}

// ---------------------------------------------------------------------------
// K4: wave-per-query fused attention. One wave per query; each wave owns a
// private 20x128 LDS slab, so waves never share DATA. Phase boundaries use
// block-uniform __syncthreads (cheap: LDS-only traffic, no global-load-lds
// queue to drain) rather than relying on wave-synchronous LDS semantics —
// the zero-barrier variant coincided with 2x container failure (R9/R10) and
// is the only untested pattern; de-risked here.
// Lane roles: phases A/C lane=channel; phase B lane=4 hidden cols.
// Register arrays indexed ONLY by fully-unrolled loop vars (R4 trap).
// NO min-waves launch-bounds arg (R5 trap: clamped to 84 VGPR -> spill).
// ---------------------------------------------------------------------------
__global__ __launch_bounds__(256) void k_attn(
    const float* __restrict__ pos, const float* __restrict__ qkv,
    const int* __restrict__ idxbuf,
    const float* __restrict__ pw1, const float* __restrict__ pb1,
    const float* __restrict__ pw2, const float* __restrict__ pb2,
    const float* __restrict__ aw1, const float* __restrict__ ab1,
    const float* __restrict__ aw2, const float* __restrict__ ab2,
    float* __restrict__ xout) {
  __shared__ float s_inp[4][KNB][128];   // 40 KB: [wave][row][c]
  __shared__ int   s_nb[4][24];          // per-wave neighbor ids

  int tid = threadIdx.x;
  int wv = tid >> 6, lane = tid & 63;
  int i = blockIdx.x * 4 + wv;           // one query per wave

  if (lane < KNB) s_nb[wv][lane] = idxbuf[i * KNB + lane];
  float qi = qkv[(size_t)i * 192 + lane];          // q_i[lane], register
  float px = pos[i * 3 + 0], py = pos[i * 3 + 1], pz = pos[i * 3 + 2];
  __syncthreads();

  // A1: t1[n][lane] = relu(rel . pw1[:,lane] + pb1[lane]) -> slab[n][0:64]
  {
    float w1x = pw1[lane], w1y = pw1[64 + lane], w1z = pw1[128 + lane];
    float b1h = pb1[lane];
#pragma unroll
    for (int n = 0; n < KNB; n++) {
      int g = s_nb[wv][n];
      float rx = px - pos[g * 3 + 0];
      float ry = py - pos[g * 3 + 1];
      float rz = pz - pos[g * 3 + 2];
      s_inp[wv][n][lane] = fmaxf(b1h + rx * w1x + ry * w1y + rz * w1z, 0.f);
    }
  }
  __syncthreads();

  // A2: rpe[n][lane] = t1[n] . pw2[:,lane] + pb2[lane] -> slab[n][64:128]
  {
    float b2c = pb2[lane];
    float racc[KNB];
#pragma unroll
    for (int n = 0; n < KNB; n++) racc[n] = b2c;
#pragma unroll
    for (int h8 = 0; h8 < 64; h8 += 8) {
      float w0 = pw2[(h8 + 0) * 64 + lane];
      float w1 = pw2[(h8 + 1) * 64 + lane];
      float w2 = pw2[(h8 + 2) * 64 + lane];
      float w3 = pw2[(h8 + 3) * 64 + lane];
      float w4 = pw2[(h8 + 4) * 64 + lane];
      float w5 = pw2[(h8 + 5) * 64 + lane];
      float w6 = pw2[(h8 + 6) * 64 + lane];
      float w7 = pw2[(h8 + 7) * 64 + lane];
#pragma unroll
      for (int n = 0; n < KNB; n++) {
        float4 ta = *(float4*)&s_inp[wv][n][h8];
        float4 tb = *(float4*)&s_inp[wv][n][h8 + 4];
        racc[n] += ta.x * w0 + ta.y * w1 + ta.z * w2 + ta.w * w3 +
                   tb.x * w4 + tb.y * w5 + tb.z * w6 + tb.w * w7;
      }
    }
#pragma unroll
    for (int n = 0; n < KNB; n++) s_inp[wv][n][64 + lane] = racc[n];
  }
  __syncthreads();

  // A3: slab[n][0:64] = q - k_gather (A2's t1 reads closed by the barrier)
#pragma unroll
  for (int n = 0; n < KNB; n++) {
    int g = s_nb[wv][n];
    float kv = qkv[(size_t)g * 192 + 64 + lane];
    s_inp[wv][n][lane] = qi - kv;
  }
  __syncthreads();

  // B: hidden(20x256) = inp @ aw1; lane owns cols 4*lane..4*lane+3.
  // aw1 streamed from global (coalesced 1KB/instr, L1/L2-hot); slab reads
  // are wave-broadcast b128 (conflict-free). No barriers inside the loop.
  int col0 = lane * 4;
  float acc[KNB][4];
#pragma unroll
  for (int n = 0; n < KNB; n++) {
    acc[n][0] = 0.f; acc[n][1] = 0.f; acc[n][2] = 0.f; acc[n][3] = 0.f;
  }
#pragma unroll 2
  for (int kc = 0; kc < 128; kc += 4) {
    float4 w0 = *(const float4*)&aw1[(size_t)(kc + 0) * 256 + col0];
    float4 w1 = *(const float4*)&aw1[(size_t)(kc + 1) * 256 + col0];
    float4 w2 = *(const float4*)&aw1[(size_t)(kc + 2) * 256 + col0];
    float4 w3 = *(const float4*)&aw1[(size_t)(kc + 3) * 256 + col0];
#pragma unroll
    for (int n = 0; n < KNB; n++) {
      float4 iv = *(float4*)&s_inp[wv][n][kc];
      acc[n][0] += iv.x * w0.x + iv.y * w1.x + iv.z * w2.x + iv.w * w3.x;
      acc[n][1] += iv.x * w0.y + iv.y * w1.y + iv.z * w2.y + iv.w * w3.y;
      acc[n][2] += iv.x * w0.z + iv.y * w1.z + iv.z * w2.z + iv.w * w3.z;
      acc[n][3] += iv.x * w0.w + iv.y * w1.w + iv.z * w2.w + iv.w * w3.w;
    }
  }

  // epilogue: sim[n] = relu(hidden+ab1).aw2 + ab2, butterfly over 64 lanes
  // (result lands in every lane -> softmax done redundantly per-lane).
  float4 b1v = *(const float4*)&ab1[col0];
  float4 w2v = *(const float4*)&aw2[col0];
  float ab2v = ab2[0];
  float sim[KNB];
#pragma unroll
  for (int n = 0; n < KNB; n++) {
    float s = fmaxf(acc[n][0] + b1v.x, 0.f) * w2v.x +
              fmaxf(acc[n][1] + b1v.y, 0.f) * w2v.y +
              fmaxf(acc[n][2] + b1v.z, 0.f) * w2v.z +
              fmaxf(acc[n][3] + b1v.w, 0.f) * w2v.w;
#pragma unroll
    for (int off = 32; off >= 1; off >>= 1) s += __shfl_xor(s, off);
    sim[n] = s + ab2v;
  }

  // C: softmax over K=20, out[lane] = sum attn * (v_gather + rpe)
  float mx = -3.402823466e38f;
#pragma unroll
  for (int n = 0; n < KNB; n++) mx = fmaxf(mx, sim[n]);
  float e[KNB];
  float sum = 0.f;
#pragma unroll
  for (int n = 0; n < KNB; n++) { e[n] = expf(sim[n] - mx); sum += e[n]; }
  float inv = 1.f / sum;
  float o = 0.f;
#pragma unroll
  for (int n = 0; n < KNB; n++) {
    int g = s_nb[wv][n];
    float vnb = qkv[(size_t)g * 192 + 128 + lane] + s_inp[wv][n][64 + lane];
    o += (e[n] * inv) * vnb;
  }
  xout[(size_t)i * 64 + lane] = o;
}

// ---------------------------------------------------------------------------
// K5: global max-pool + fc1 + fc3 (unchanged)
// ---------------------------------------------------------------------------
__global__ __launch_bounds__(256) void k_final(const float* __restrict__ x,
                                               const float* __restrict__ fc1w,
                                               const float* __restrict__ fc1b,
                                               const float* __restrict__ fc3w,
                                               const float* __restrict__ fc3b,
                                               float* __restrict__ out) {
  __shared__ float red[4][64];
  __shared__ float m[64];
  __shared__ float h1[32];
  int b = blockIdx.x;
  int tid = threadIdx.x;
  int c = tid & 63, pg = tid >> 6;
  float mx = -3.402823466e38f;
  for (int p = pg; p < NPTS; p += 4)
    mx = fmaxf(mx, x[((size_t)b * NPTS + p) * 64 + c]);
  red[pg][c] = mx;
  __syncthreads();
  if (tid < 64)
    m[c] = fmaxf(fmaxf(red[0][c], red[1][c]), fmaxf(red[2][c], red[3][c]));
  __syncthreads();
  if (tid < 32) {
    float a = fc1b[tid];
#pragma unroll 8
    for (int k = 0; k < 64; k++) a += m[k] * fc1w[k * 32 + tid];
    h1[tid] = fmaxf(a, 0.f);
  }
  __syncthreads();
  if (tid < 3) {
    float a = fc3b[tid];
#pragma unroll
    for (int k = 0; k < 32; k++) a += h1[k] * fc3w[k * 3 + tid];
    out[b * 3 + tid] = a;
  }
}

// ---------------------------------------------------------------------------
// Workspace: x0 @0 (4MB) | idx @4MB (1.3MB) | qkv @6MB (12.6MB)
//            x1 @19MB (4.2MB) | x2 @23.2MB (4.2MB)
// ---------------------------------------------------------------------------
extern "C" void kernel_launch(void* const* d_in, const int* in_sizes, int n_in,
                              void* d_out, int out_size, void* d_ws,
                              size_t ws_size, hipStream_t stream) {
  const float* pts    = (const float*)d_in[0];
  const float* conv_w = (const float*)d_in[1];
  const float* conv_b = (const float*)d_in[2];
  const float* fc1w = (const float*)d_in[21];
  const float* fc1b = (const float*)d_in[22];
  const float* fc3w = (const float*)d_in[23];
  const float* fc3b = (const float*)d_in[24];
  float* outp = (float*)d_out;

  char* ws = (char*)d_ws;
  float* x0  = (float*)(ws);
  int*   idx = (int*)  (ws + (size_t)4 * 1048576);
  float* qkv = (float*)(ws + (size_t)6 * 1048576);
  float* x1  = (float*)(ws + (size_t)19 * 1048576);
  float* x2  = (float*)(ws + (size_t)19 * 1048576 + 4194304);

  k_conv<<<(TOTAL * 64 + 255) / 256, 256, 0, stream>>>(pts, conv_w, conv_b, x0);
  k_knn<<<TOTAL / 4, 256, 0, stream>>>(pts, idx);

  // layer 1
  {
    const float* qkvw = (const float*)d_in[3];
    k_qkv<<<(TOTAL * 48 + 255) / 256, 256, 0, stream>>>(x0, qkvw, qkv);
    k_attn<<<TOTAL / 4, 256, 0, stream>>>(
        pts, qkv, idx, (const float*)d_in[4], (const float*)d_in[5],
        (const float*)d_in[6], (const float*)d_in[7], (const float*)d_in[8],
        (const float*)d_in[9], (const float*)d_in[10], (const float*)d_in[11],
        x1);
  }
  // layer 2
  {
    const float* qkvw = (const float*)d_in[12];
    k_qkv<<<(TOTAL * 48 + 255) / 256, 256, 0, stream>>>(x1, qkvw, qkv);
    k_attn<<<TOTAL / 4, 256, 0, stream>>>(
        pts, qkv, idx, (const float*)d_in[13], (const float*)d_in[14],
        (const float*)d_in[15], (const float*)d_in[16], (const float*)d_in[17],
        (const float*)d_in[18], (const float*)d_in[19], (const float*)d_in[20],
        x2);
  }
  k_final<<<BATCH, 256, 0, stream>>>(x2, fc1w, fc1b, fc3w, fc3b, outp);
}